// Round 7
// baseline (1252.686 us; speedup 1.0000x reference)
//
#include <hip/hip_runtime.h>
#include <hip/hip_bf16.h>

typedef __hip_bfloat16 bf16;
typedef __attribute__((ext_vector_type(8))) short short8;
typedef __attribute__((ext_vector_type(4))) float floatx4;

#define NNODES 118784
#define NEDGES 3000000
#define INDIM 116
#define EMBD 16
#define HID 64
#define NGRAPH 1024
#define ROIS 116
#define NBINS 1024      // 116 nodes per bin
#define BCAP 3456       // per-bin LDS staging cap (mean 2930, sd 54 -> +9.7 sigma)
#define CBLK 4096       // edges per counting/placement block
#define NBLKC 733       // ceil(NEDGES / CBLK)
#define NBLKC_PAD 736

__device__ __forceinline__ float b2f(bf16 v) { return __bfloat162float(v); }
__device__ __forceinline__ bf16 f2b(float v) { return __float2bfloat16(v); }
__device__ __forceinline__ unsigned f2u(float v) {
    bf16 b = __float2bfloat16(v);
    return (unsigned)*reinterpret_cast<unsigned short*>(&b);
}
__device__ __forceinline__ float uf(unsigned u) { return __uint_as_float(u); }

// ---------------------------------------------------------------------------
// Sort 1: per-(block,bin) histogram -> cntMat[bin][blk]. No global atomics.
// ---------------------------------------------------------------------------
__global__ __launch_bounds__(256) void bincnt_kernel(
    const int* __restrict__ dst, int* __restrict__ cntMat)
{
    __shared__ int h[NBINS];
    for (int i = threadIdx.x; i < NBINS; i += 256) h[i] = 0;
    __syncthreads();
    const int base = blockIdx.x * CBLK;
    const int end = min(base + CBLK, NEDGES);
    for (int i = base + threadIdx.x; i < end; i += 256)
        atomicAdd(&h[(unsigned)dst[i] / 116u], 1);
    __syncthreads();
    for (int i = threadIdx.x; i < NBINS; i += 256)
        cntMat[i * NBLKC_PAD + blockIdx.x] = h[i];
}

// ---------------------------------------------------------------------------
// Sort 2: per-bin exclusive scan across blocks (in place), totals -> binCnt.
// ---------------------------------------------------------------------------
__global__ __launch_bounds__(256) void colscan_kernel(
    int* __restrict__ cntMat, int* __restrict__ binCnt)
{
    __shared__ int sd[256];
    int* row = cntMat + blockIdx.x * NBLKC_PAD;
    const int t = threadIdx.x;
    int v[3]; int s = 0;
    #pragma unroll
    for (int j = 0; j < 3; j++) {
        const int idx = t * 3 + j;
        v[j] = (idx < NBLKC) ? row[idx] : 0;
        s += v[j];
    }
    sd[t] = s;
    __syncthreads();
    for (int d = 1; d < 256; d <<= 1) {
        int x = (t >= d) ? sd[t - d] : 0;
        __syncthreads();
        sd[t] += x;
        __syncthreads();
    }
    int ex = (t == 0) ? 0 : sd[t - 1];
    #pragma unroll
    for (int j = 0; j < 3; j++) {
        const int idx = t * 3 + j;
        if (idx < NBLKC) { const int val = v[j]; row[idx] = ex; ex += val; }
    }
    if (t == 255) binCnt[blockIdx.x] = ex;
}

// ---------------------------------------------------------------------------
// Sort 3: exclusive scan of 1024 bin totals (1 block)
// ---------------------------------------------------------------------------
__global__ __launch_bounds__(256) void binscan_kernel(
    const int* __restrict__ binCnt, int* __restrict__ binOff,
    int* __restrict__ offN)
{
    __shared__ int sd[256];
    const int t = threadIdx.x;
    int c[4]; int s = 0;
    #pragma unroll
    for (int j = 0; j < 4; j++) { c[j] = binCnt[t * 4 + j]; s += c[j]; }
    sd[t] = s;
    __syncthreads();
    for (int d = 1; d < 256; d <<= 1) {
        int v = (t >= d) ? sd[t - d] : 0;
        __syncthreads();
        sd[t] += v;
        __syncthreads();
    }
    int ex = (t == 0) ? 0 : sd[t - 1];
    #pragma unroll
    for (int j = 0; j < 4; j++) { binOff[t * 4 + j] = ex; ex += c[j]; }
    if (t == 0) { binOff[NBINS] = NEDGES; offN[0] = NEDGES; }
}

// ---------------------------------------------------------------------------
// Sort 4: deterministic placement. LDS cursors seeded from cntMat+binOff;
// zero global atomics. record = {src | dstLocal<<20, ea0|ea1, ea2|ea3, ea4}
// ---------------------------------------------------------------------------
__global__ __launch_bounds__(256) void binplace_kernel(
    const int* __restrict__ src, const int* __restrict__ dst,
    const float* __restrict__ ea, const int* __restrict__ posMat,
    const int* __restrict__ binOff, uint4* __restrict__ rec)
{
    __shared__ int cursor[NBINS];
    const int blk = blockIdx.x;
    for (int i = threadIdx.x; i < NBINS; i += 256)
        cursor[i] = posMat[i * NBLKC_PAD + blk] + binOff[i];
    __syncthreads();
    const int base = blk * CBLK;
    const int end = min(base + CBLK, NEDGES);
    for (int e = base + threadIdx.x; e < end; e += 256) {
        const unsigned d = (unsigned)dst[e];
        const unsigned bin = d / 116u;
        const unsigned dl = d - bin * 116u;
        const float* a = ea + (size_t)e * 5;
        const unsigned m0 = f2u(a[0]) | (f2u(a[1]) << 16);
        const unsigned m1 = f2u(a[2]) | (f2u(a[3]) << 16);
        const unsigned m2 = f2u(a[4]);
        const int p = atomicAdd(&cursor[bin], 1);
        rec[p] = make_uint4((unsigned)src[e] | (dl << 20), m0, m1, m2);
    }
}

// ---------------------------------------------------------------------------
// Sort 5: in-place per-bin sort by local node (block per bin, bin staged in
// LDS), emits final per-node CSR offsets. Final records carry src*128
// (byte offset of the 128B h-row) for add-only gather addressing in agg.
// ---------------------------------------------------------------------------
__global__ __launch_bounds__(256) void binsort_kernel(
    uint4* __restrict__ rec, const int* __restrict__ binOff,
    int* __restrict__ off)
{
    __shared__ uint4 buf[BCAP];
    __shared__ int cnt[128];
    __shared__ int sc[128];
    const int b = blockIdx.x, t = threadIdx.x;
    const int n0 = binOff[b];
    const int n  = binOff[b + 1] - n0;
    if (t < 128) cnt[t] = 0;
    __syncthreads();
    for (int i = t; i < n; i += 256) {
        uint4 r = rec[n0 + i];
        buf[i] = r;
        atomicAdd(&cnt[r.x >> 20], 1);
    }
    __syncthreads();
    if (t < 128) sc[t] = cnt[t];
    __syncthreads();
    for (int d = 1; d < 128; d <<= 1) {
        int v = 0;
        if (t < 128 && t >= d) v = sc[t - d];
        __syncthreads();
        if (t < 128) sc[t] += v;
        __syncthreads();
    }
    if (t < 116) {
        const int ex = sc[t] - cnt[t];
        off[b * 116 + t] = n0 + ex;
        cnt[t] = ex;                      // reuse as cursor
    }
    __syncthreads();
    for (int i = t; i < n; i += 256) {
        uint4 r = buf[i];
        const int p = atomicAdd(&cnt[r.x >> 20], 1);
        r.x = (r.x & 0xFFFFFu) << 7;      // src -> byte offset of h-row
        rec[n0 + p] = r;
    }
}

// ---------------------------------------------------------------------------
// One-time weight packer: bf16 MFMA-fragment layouts in workspace.
// ---------------------------------------------------------------------------
__global__ __launch_bounds__(256) void pack_kernel(
    const float* __restrict__ Wenc,
    const float* __restrict__ W10, const float* __restrict__ W20,
    const float* __restrict__ W1, const float* __restrict__ W2,
    unsigned short* __restrict__ WPenc, unsigned short* __restrict__ WPh)
{
    const int b = blockIdx.x, tid = threadIdx.x;
    if (b == 0) {
        for (int i = tid; i < 10240; i += 256) {
            const int j = i & 7, lane = (i >> 3) & 63, t = i >> 9;
            const int c = t / 5, s = t - c * 5;
            const int k = s * 32 + (lane >> 4) * 8 + j;
            const int n = c * 16 + (lane & 15);
            const float v = (k < 132) ? Wenc[k * 64 + n] : 0.f;
            WPenc[i] = (unsigned short)f2u(v);
        }
        return;
    }
    const float* src = nullptr;
    unsigned short* dst = nullptr;
    switch (b) {
        case 1: src = W10;       dst = WPh + 0 * 4096; break;
        case 2: src = W20;       dst = WPh + 1 * 4096; break;
        case 3: src = W1;        dst = WPh + 2 * 4096; break;
        case 4: src = W2;        dst = WPh + 3 * 4096; break;
        case 5: src = W1 + 4096; dst = WPh + 4 * 4096; break;
        case 6: src = W2 + 4096; dst = WPh + 5 * 4096; break;
        case 7: src = W1 + 8192; dst = WPh + 6 * 4096; break;
        case 8: src = W2 + 8192; dst = WPh + 7 * 4096; break;
    }
    for (int i = tid; i < 4096; i += 256) {
        const int j = i & 7, lane = (i >> 3) & 63, t = i >> 9;
        const int c = t >> 1, s = t & 1;
        const int k = s * 32 + (lane >> 4) * 8 + j;
        const int n = c * 16 + (lane & 15);
        dst[i] = (unsigned short)f2u(src[k * 64 + n]);
    }
}

// ---------------------------------------------------------------------------
// Encoder GEMM, LDS-free: A fragments built from global x/emb via float4,
// B fragments read from prepacked global (L2-broadcast). No staging barriers.
// ---------------------------------------------------------------------------
__global__ __launch_bounds__(256) void enc_kernel(
    const float* __restrict__ x, const int* __restrict__ gid,
    const float* __restrict__ emb, const unsigned short* __restrict__ WP,
    const float* __restrict__ benc,
    bf16* __restrict__ hb, float* __restrict__ stats)
{
    __shared__ float sred[4][128];

    const int tid  = threadIdx.x;
    const int lane = tid & 63;
    const int wv   = tid >> 6;
    const int m    = lane & 15;
    const int q    = lane >> 4;
    const int r0   = blockIdx.x * 64;

    const int arow = r0 + wv * 16 + m;
    const float* xr = x + (size_t)arow * INDIM;
    const float* er = emb + gid[arow] * EMBD;

    floatx4 acc[4];
    #pragma unroll
    for (int c = 0; c < 4; c++) acc[c] = {0.f, 0.f, 0.f, 0.f};

    #pragma unroll
    for (int s = 0; s < 5; s++) {
        float4 a, b;
        if (s < 3) {                                    // k in [0,96): pure x
            a = *(const float4*)(xr + s * 32 + q * 8);
            b = *(const float4*)(xr + s * 32 + q * 8 + 4);
        } else if (s == 3) {                            // k in [96,128): seam
            if (q < 2) {
                a = *(const float4*)(xr + 96 + q * 8);
                b = *(const float4*)(xr + 100 + q * 8);
            } else if (q == 2) {
                a = *(const float4*)(xr + 112);
                b = *(const float4*)(er);
            } else {
                a = *(const float4*)(er + 4);
                b = *(const float4*)(er + 8);
            }
        } else {                                        // k in [128,160)
            if (q == 0) {
                a = *(const float4*)(er + 12);
                b = make_float4(0.f, 0.f, 0.f, 0.f);
            } else {
                a = make_float4(0.f, 0.f, 0.f, 0.f);
                b = a;
            }
        }
        short8 af;
        af[0] = (short)f2u(a.x); af[1] = (short)f2u(a.y);
        af[2] = (short)f2u(a.z); af[3] = (short)f2u(a.w);
        af[4] = (short)f2u(b.x); af[5] = (short)f2u(b.y);
        af[6] = (short)f2u(b.z); af[7] = (short)f2u(b.w);
        #pragma unroll
        for (int c = 0; c < 4; c++) {
            short8 bfr = *(const short8*)(WP + (size_t)(((c * 5 + s) * 64) + lane) * 8);
            acc[c] = __builtin_amdgcn_mfma_f32_16x16x32_bf16(af, bfr, acc[c], 0, 0, 0);
        }
    }

    #pragma unroll
    for (int c = 0; c < 4; c++) {
        const int ch = c * 16 + m;
        const float bb = benc[ch];
        float sv = 0.f, sq = 0.f;
        #pragma unroll
        for (int r = 0; r < 4; r++) {
            const int orow = r0 + wv * 16 + q * 4 + r;
            float a = fmaxf(acc[c][r] + bb, 0.f);
            hb[(size_t)orow * HID + ch] = f2b(a);
            sv += a; sq += a * a;
        }
        sv += __shfl_xor(sv, 16); sv += __shfl_xor(sv, 32);
        sq += __shfl_xor(sq, 16); sq += __shfl_xor(sq, 32);
        if (q == 0) { sred[wv][ch] = sv; sred[wv][64 + ch] = sq; }
    }
    __syncthreads();
    if (tid < 128) {
        const float s = sred[0][tid] + sred[1][tid] + sred[2][tid] + sred[3][tid];
        unsafeAtomicAdd(&stats[tid], s);
    }
}

// ---------------------------------------------------------------------------
// Fused GINE layer: gather-aggregate (wave per 16 nodes) writing z rows
// straight into the LDS tile, then the MFMA node-MLP on that tile.
// Each wave's 16 z-rows are exactly the rows its MLP quarter consumes, so no
// inter-phase barrier is needed. LDS = Zl+Tl = 18432B (sred removed) ->
// 8 blocks/CU -> capacity 2048 blocks >= grid 1856: whole grid co-resident
// in ONE scheduling round (kills the r6 quantization tail). Stats use direct
// per-wave atomics; no trailing __syncthreads.
// AMODE: 0 = identity, 1 = BN, 2 = BN+relu (applied to hin reads)
// MMODE: 0 = relu output.  1 = pre-BN output + stats.
// ---------------------------------------------------------------------------
template <int AMODE, int MMODE>
__global__ __launch_bounds__(256) void gine_kernel(
    const bf16* __restrict__ hin, bf16* __restrict__ zout,
    const uint4* __restrict__ rec, const int* __restrict__ off,
    const float* __restrict__ We, const float* __restrict__ be,
    const float* __restrict__ statsIn, const float* __restrict__ gamma,
    const float* __restrict__ beta,
    const unsigned short* __restrict__ W1P, const float* __restrict__ b1,
    const unsigned short* __restrict__ W2P, const float* __restrict__ b2,
    float* __restrict__ statsOut)
{
    __shared__ unsigned short Zl[64 * 72];
    __shared__ unsigned short Tl[64 * 72];

    const int tid  = threadIdx.x;
    const int lane = tid & 63;
    const int wv   = __builtin_amdgcn_readfirstlane(tid >> 6);
    const int r0   = blockIdx.x * 64;

    // ================= phase 1: aggregate 16 nodes (this wave) =============
    {
        float gg = 1.f, bbt = 0.f;
        if (AMODE != 0) {
            const float m = statsIn[lane] * (1.f / NNODES);
            const float var = statsIn[64 + lane] * (1.f / NNODES) - m * m;
            const float inv = rsqrtf(var + 1e-5f);
            gg = gamma[lane] * inv;
            bbt = beta[lane] - gg * m;
        }
        const float w0 = We[lane], w1 = We[64 + lane], w2 = We[128 + lane];
        const float w3 = We[192 + lane], w4 = We[256 + lane];
        const float bel = be[lane];

        // record.x holds the h-row byte offset; per-lane part is lane*2
        const char* hlane = (const char*)hin + (lane << 1);

        for (int t = 0; t < 16; t++) {
            const int node = r0 + wv * 16 + t;
            const int s0 = off[node];
            const int s1 = off[node + 1];

            float self = b2f(hin[(size_t)node * HID + lane]);
            if (AMODE == 1) self = gg * self + bbt;
            if (AMODE == 2) self = fmaxf(gg * self + bbt, 0.f);

            float acc = 0.f;
            int i = s0;

#define EDGE_TERM(R, HF)                                                     \
    {                                                                        \
        float hh = (HF);                                                     \
        if (AMODE == 1) hh = gg * hh + bbt;                                  \
        if (AMODE == 2) hh = fmaxf(gg * hh + bbt, 0.f);                      \
        const float v = bel                                                  \
            + uf((R).y << 16) * w0 + uf((R).y & 0xFFFF0000u) * w1            \
            + uf((R).z << 16) * w2 + uf((R).z & 0xFFFF0000u) * w3            \
            + uf((R).w << 16) * w4 + hh;                                     \
        acc += fmaxf(v, 0.f);                                                \
    }

            for (; i + 8 <= s1; i += 8) {
                uint4 r[8];
                #pragma unroll
                for (int j = 0; j < 8; j++) r[j] = rec[i + j];
                float h[8];
                #pragma unroll
                for (int j = 0; j < 8; j++)
                    h[j] = uf((unsigned)*(const unsigned short*)(hlane + r[j].x) << 16);
                #pragma unroll
                for (int j = 0; j < 8; j++) EDGE_TERM(r[j], h[j])
            }
            for (; i + 4 <= s1; i += 4) {
                uint4 r[4];
                #pragma unroll
                for (int j = 0; j < 4; j++) r[j] = rec[i + j];
                float h[4];
                #pragma unroll
                for (int j = 0; j < 4; j++)
                    h[j] = uf((unsigned)*(const unsigned short*)(hlane + r[j].x) << 16);
                #pragma unroll
                for (int j = 0; j < 4; j++) EDGE_TERM(r[j], h[j])
            }
            for (; i < s1; i++) {
                const uint4 r = rec[i];
                const float hf = uf((unsigned)*(const unsigned short*)(hlane + r.x) << 16);
                EDGE_TERM(r, hf)
            }
#undef EDGE_TERM

            Zl[(wv * 16 + t) * 72 + lane] = (unsigned short)f2u(self + acc);
        }
    }

    // ================= phase 2: node MLP on this wave's 16 rows =============
    const int m    = lane & 15;
    const int q    = lane >> 4;
    const int mrow = wv * 16;

    float bias1[4], bias2[4];
    #pragma unroll
    for (int c = 0; c < 4; c++) {
        bias1[c] = b1[c * 16 + m];
        bias2[c] = b2[c * 16 + m];
    }

    floatx4 acc[4];
    #pragma unroll
    for (int c = 0; c < 4; c++) acc[c] = {0.f, 0.f, 0.f, 0.f};
    #pragma unroll
    for (int s = 0; s < 2; s++) {
        short8 af = *(const short8*)&Zl[(mrow + m) * 72 + s * 32 + q * 8];
        #pragma unroll
        for (int c = 0; c < 4; c++) {
            short8 bfr = *(const short8*)(W1P + (size_t)(((c * 2 + s) * 64) + lane) * 8);
            acc[c] = __builtin_amdgcn_mfma_f32_16x16x32_bf16(af, bfr, acc[c], 0, 0, 0);
        }
    }
    #pragma unroll
    for (int c = 0; c < 4; c++)
        #pragma unroll
        for (int r = 0; r < 4; r++)
            Tl[(mrow + q * 4 + r) * 72 + c * 16 + m] =
                (unsigned short)f2u(fmaxf(acc[c][r] + bias1[c], 0.f));

    #pragma unroll
    for (int c = 0; c < 4; c++) acc[c] = {0.f, 0.f, 0.f, 0.f};
    #pragma unroll
    for (int s = 0; s < 2; s++) {
        short8 af = *(const short8*)&Tl[(mrow + m) * 72 + s * 32 + q * 8];
        #pragma unroll
        for (int c = 0; c < 4; c++) {
            short8 bfr = *(const short8*)(W2P + (size_t)(((c * 2 + s) * 64) + lane) * 8);
            acc[c] = __builtin_amdgcn_mfma_f32_16x16x32_bf16(af, bfr, acc[c], 0, 0, 0);
        }
    }
    #pragma unroll
    for (int c = 0; c < 4; c++) {
        float sv = 0.f, sq = 0.f;
        #pragma unroll
        for (int r = 0; r < 4; r++) {
            float o = acc[c][r] + bias2[c];
            if (MMODE == 0) o = fmaxf(o, 0.f);
            zout[(size_t)(r0 + mrow + q * 4 + r) * HID + c * 16 + m] = f2b(o);
            if (MMODE == 1) { sv += o; sq += o * o; }
        }
        if (MMODE == 1) {
            sv += __shfl_xor(sv, 16); sv += __shfl_xor(sv, 32);
            sq += __shfl_xor(sq, 16); sq += __shfl_xor(sq, 32);
            if (q == 0) {
                unsafeAtomicAdd(&statsOut[c * 16 + m], sv);
                unsafeAtomicAdd(&statsOut[64 + c * 16 + m], sq);
            }
        }
    }
}

// ---------------------------------------------------------------------------
// Head with fused final BN+relu
// ---------------------------------------------------------------------------
__global__ __launch_bounds__(128) void head_kernel(
    const bf16* __restrict__ hb, const float* __restrict__ Wl1,
    const float* __restrict__ bl1, const float* __restrict__ Wl2,
    const float* __restrict__ bl2, float* __restrict__ out,
    const float* __restrict__ stats, const float* __restrict__ gamma,
    const float* __restrict__ beta)
{
    __shared__ float part[2 * HID];
    __shared__ float ps[HID];
    __shared__ float r0[128], r1[128];

    const int g = blockIdx.x;
    const int tid = threadIdx.x;
    const int lane = tid & 63;
    const int wv = tid >> 6;
    const bf16* hbg = hb + (size_t)g * ROIS * HID;

    const float mm = stats[lane] * (1.f / NNODES);
    const float var = stats[64 + lane] * (1.f / NNODES) - mm * mm;
    const float inv = rsqrtf(var + 1e-5f);
    const float gg = gamma[lane] * inv;
    const float bbt = beta[lane] - gg * mm;

    float acc = 0.f;
    for (int r = wv; r < ROIS; r += 2)
        acc += fmaxf(gg * b2f(hbg[r * HID + lane]) + bbt, 0.f);
    part[wv * HID + lane] = acc;
    __syncthreads();
    if (tid < HID) ps[tid] = fmaxf(part[tid] + part[HID + tid], 0.f);
    __syncthreads();

    float e0 = 0.f, e1 = 0.f;
    if (tid < ROIS) {
        float a = bl1[tid];
        #pragma unroll 8
        for (int c = 0; c < HID; c++)
            a += ps[c] * Wl1[c * ROIS + tid];
        e0 = a * Wl2[tid * 2 + 0];
        e1 = a * Wl2[tid * 2 + 1];
    }
    r0[tid] = e0;
    r1[tid] = e1;
    __syncthreads();
    for (int s = 64; s > 0; s >>= 1) {
        if (tid < s) { r0[tid] += r0[tid + s]; r1[tid] += r1[tid + s]; }
        __syncthreads();
    }
    if (tid == 0) {
        out[g * 2 + 0] = r0[0] + bl2[0];
        out[g * 2 + 1] = r1[0] + bl2[1];
    }
}

// ---------------------------------------------------------------------------
extern "C" void kernel_launch(void* const* d_in, const int* in_sizes, int n_in,
                              void* d_out, int out_size, void* d_ws, size_t ws_size,
                              hipStream_t stream)
{
    const float* x       = (const float*)d_in[0];
    const float* ea      = (const float*)d_in[1];
    const int*   eidx    = (const int*)  d_in[2];
    const int*   gid     = (const int*)  d_in[4];
    const float* emb     = (const float*)d_in[5];
    const float* Wenc    = (const float*)d_in[6];
    const float* benc    = (const float*)d_in[7];
    const float* gamma_e = (const float*)d_in[8];
    const float* beta_e  = (const float*)d_in[9];
    const float* We0     = (const float*)d_in[10];
    const float* be0     = (const float*)d_in[11];
    const float* W10     = (const float*)d_in[12];
    const float* b10     = (const float*)d_in[13];
    const float* W20     = (const float*)d_in[14];
    const float* b20     = (const float*)d_in[15];
    const float* We      = (const float*)d_in[16];
    const float* be      = (const float*)d_in[17];
    const float* W1      = (const float*)d_in[18];
    const float* b1      = (const float*)d_in[19];
    const float* W2      = (const float*)d_in[20];
    const float* b2      = (const float*)d_in[21];
    const float* gamma   = (const float*)d_in[22];
    const float* beta    = (const float*)d_in[23];
    const float* Wl1     = (const float*)d_in[24];
    const float* bl1     = (const float*)d_in[25];
    const float* Wl2     = (const float*)d_in[26];
    const float* bl2     = (const float*)d_in[27];

    const int* srcp = eidx;
    const int* dstp = eidx + NEDGES;

    // workspace (~82 MB):
    // A | Z | rec | off | binCnt | binOff | cntMat | stats | WPenc | WPh
    const size_t NH = (size_t)NNODES * HID;
    char* p = (char*)d_ws;
    bf16*  Abuf = (bf16*)p;  p += NH * 2;
    bf16*  Zbuf = (bf16*)p;  p += NH * 2;
    uint4* rec  = (uint4*)p; p += (size_t)NEDGES * 16;
    int* off    = (int*)p;   p += (size_t)(NNODES + 16) * 4;
    int* binCnt = (int*)p;   p += (NBINS + 16) * 4;
    int* binOff = (int*)p;   p += (NBINS + 16) * 4;
    int* cntMat = (int*)p;   p += (size_t)NBINS * NBLKC_PAD * 4;
    float* stats = (float*)p; p += 512 * 4;
    unsigned short* WPenc = (unsigned short*)p; p += 10240 * 2;
    unsigned short* WPh   = (unsigned short*)p; p += 8 * 4096 * 2;

    hipMemsetAsync(stats, 0, 512 * 4, stream);

    const int gb = NNODES / 64;                // 1856 blocks, 64 nodes each

    // ---- one-time weight packing (overlaps the edge sort) ----
    pack_kernel<<<9, 256, 0, stream>>>(Wenc, W10, W20, W1, W2, WPenc, WPh);

    // ---- counting-sort of edges by dst (no global atomics) ----
    bincnt_kernel<<<NBLKC, 256, 0, stream>>>(dstp, cntMat);
    colscan_kernel<<<NBINS, 256, 0, stream>>>(cntMat, binCnt);
    binscan_kernel<<<1, 256, 0, stream>>>(binCnt, binOff, off + NNODES);
    binplace_kernel<<<NBLKC, 256, 0, stream>>>(srcp, dstp, ea, cntMat, binOff, rec);
    binsort_kernel<<<NBINS, 256, 0, stream>>>(rec, binOff, off);

    // ---- encoder (pre-BN + stats0) ----
    enc_kernel<<<NNODES / 64, 256, 0, stream>>>(x, gid, emb, WPenc, benc, Abuf, stats);

    // ---- GINE layer 0: T = BN_e (no relu); mlp relu ----
    gine_kernel<1, 0><<<gb, 256, 0, stream>>>(
        Abuf, Zbuf, rec, off, We0, be0, stats, gamma_e, beta_e,
        WPh + 0 * 4096, b10, WPh + 1 * 4096, b20, nullptr);

    // ---- GINE layer 1: identity T (input already relu'd); stats1 ----
    gine_kernel<0, 1><<<gb, 256, 0, stream>>>(
        Zbuf, Abuf, rec, off, We, be, nullptr, nullptr, nullptr,
        WPh + 2 * 4096, b1, WPh + 3 * 4096, b2, stats + 128);

    // ---- GINE layer 2: T = BN+relu (stats1); stats2 ----
    gine_kernel<2, 1><<<gb, 256, 0, stream>>>(
        Abuf, Zbuf, rec, off, We + 320, be + 64, stats + 128, gamma, beta,
        WPh + 4 * 4096, b1 + 64, WPh + 5 * 4096, b2 + 64, stats + 256);

    // ---- GINE layer 3: T = BN+relu (stats2); stats3 ----
    gine_kernel<2, 1><<<gb, 256, 0, stream>>>(
        Zbuf, Abuf, rec, off, We + 640, be + 128, stats + 256, gamma, beta,
        WPh + 6 * 4096, b1 + 128, WPh + 7 * 4096, b2 + 128, stats + 384);

    // ---- pooling + head (fused final BN+relu, stats3) ----
    head_kernel<<<NGRAPH, 128, 0, stream>>>(Abuf, Wl1, bl1, Wl2, bl2,
                                            (float*)d_out, stats + 384, gamma, beta);
}

// Round 8
// 868.206 us; speedup vs baseline: 1.4428x; 1.4428x over previous
//
#include <hip/hip_runtime.h>
#include <hip/hip_bf16.h>

typedef __hip_bfloat16 bf16;
typedef __attribute__((ext_vector_type(8))) short short8;
typedef __attribute__((ext_vector_type(4))) float floatx4;

#define NNODES 118784
#define NEDGES 3000000
#define INDIM 116
#define EMBD 16
#define HID 64
#define NGRAPH 1024
#define ROIS 116
#define NBINS 1024      // 116 nodes per bin
#define BCAP 3456       // per-bin LDS staging cap (mean 2930, sd 54 -> +9.7 sigma)
#define CBLK 4096       // edges per counting/placement block
#define NBLKC 733       // ceil(NEDGES / CBLK)
#define NBLKC_PAD 736

__device__ __forceinline__ float b2f(bf16 v) { return __bfloat162float(v); }
__device__ __forceinline__ bf16 f2b(float v) { return __float2bfloat16(v); }
__device__ __forceinline__ unsigned f2u(float v) {
    bf16 b = __float2bfloat16(v);
    return (unsigned)*reinterpret_cast<unsigned short*>(&b);
}
__device__ __forceinline__ float uf(unsigned u) { return __uint_as_float(u); }

// ---------------------------------------------------------------------------
// Sort 1: per-(block,bin) histogram -> cntMat[bin][blk]. No global atomics.
// ---------------------------------------------------------------------------
__global__ __launch_bounds__(256) void bincnt_kernel(
    const int* __restrict__ dst, int* __restrict__ cntMat)
{
    __shared__ int h[NBINS];
    for (int i = threadIdx.x; i < NBINS; i += 256) h[i] = 0;
    __syncthreads();
    const int base = blockIdx.x * CBLK;
    const int end = min(base + CBLK, NEDGES);
    for (int i = base + threadIdx.x; i < end; i += 256)
        atomicAdd(&h[(unsigned)dst[i] / 116u], 1);
    __syncthreads();
    for (int i = threadIdx.x; i < NBINS; i += 256)
        cntMat[i * NBLKC_PAD + blockIdx.x] = h[i];
}

// ---------------------------------------------------------------------------
// Sort 2: per-bin exclusive scan across blocks (in place), totals -> binCnt.
// ---------------------------------------------------------------------------
__global__ __launch_bounds__(256) void colscan_kernel(
    int* __restrict__ cntMat, int* __restrict__ binCnt)
{
    __shared__ int sd[256];
    int* row = cntMat + blockIdx.x * NBLKC_PAD;
    const int t = threadIdx.x;
    int v[3]; int s = 0;
    #pragma unroll
    for (int j = 0; j < 3; j++) {
        const int idx = t * 3 + j;
        v[j] = (idx < NBLKC) ? row[idx] : 0;
        s += v[j];
    }
    sd[t] = s;
    __syncthreads();
    for (int d = 1; d < 256; d <<= 1) {
        int x = (t >= d) ? sd[t - d] : 0;
        __syncthreads();
        sd[t] += x;
        __syncthreads();
    }
    int ex = (t == 0) ? 0 : sd[t - 1];
    #pragma unroll
    for (int j = 0; j < 3; j++) {
        const int idx = t * 3 + j;
        if (idx < NBLKC) { const int val = v[j]; row[idx] = ex; ex += val; }
    }
    if (t == 255) binCnt[blockIdx.x] = ex;
}

// ---------------------------------------------------------------------------
// Sort 3: exclusive scan of 1024 bin totals (1 block)
// ---------------------------------------------------------------------------
__global__ __launch_bounds__(256) void binscan_kernel(
    const int* __restrict__ binCnt, int* __restrict__ binOff,
    int* __restrict__ offN)
{
    __shared__ int sd[256];
    const int t = threadIdx.x;
    int c[4]; int s = 0;
    #pragma unroll
    for (int j = 0; j < 4; j++) { c[j] = binCnt[t * 4 + j]; s += c[j]; }
    sd[t] = s;
    __syncthreads();
    for (int d = 1; d < 256; d <<= 1) {
        int v = (t >= d) ? sd[t - d] : 0;
        __syncthreads();
        sd[t] += v;
        __syncthreads();
    }
    int ex = (t == 0) ? 0 : sd[t - 1];
    #pragma unroll
    for (int j = 0; j < 4; j++) { binOff[t * 4 + j] = ex; ex += c[j]; }
    if (t == 0) { binOff[NBINS] = NEDGES; offN[0] = NEDGES; }
}

// ---------------------------------------------------------------------------
// Sort 4: deterministic placement. LDS cursors seeded from cntMat+binOff;
// zero global atomics. record = {src | dstLocal<<20, ea0|ea1, ea2|ea3, ea4}
// ---------------------------------------------------------------------------
__global__ __launch_bounds__(256) void binplace_kernel(
    const int* __restrict__ src, const int* __restrict__ dst,
    const float* __restrict__ ea, const int* __restrict__ posMat,
    const int* __restrict__ binOff, uint4* __restrict__ rec)
{
    __shared__ int cursor[NBINS];
    const int blk = blockIdx.x;
    for (int i = threadIdx.x; i < NBINS; i += 256)
        cursor[i] = posMat[i * NBLKC_PAD + blk] + binOff[i];
    __syncthreads();
    const int base = blk * CBLK;
    const int end = min(base + CBLK, NEDGES);
    for (int e = base + threadIdx.x; e < end; e += 256) {
        const unsigned d = (unsigned)dst[e];
        const unsigned bin = d / 116u;
        const unsigned dl = d - bin * 116u;
        const float* a = ea + (size_t)e * 5;
        const unsigned m0 = f2u(a[0]) | (f2u(a[1]) << 16);
        const unsigned m1 = f2u(a[2]) | (f2u(a[3]) << 16);
        const unsigned m2 = f2u(a[4]);
        const int p = atomicAdd(&cursor[bin], 1);
        rec[p] = make_uint4((unsigned)src[e] | (dl << 20), m0, m1, m2);
    }
}

// ---------------------------------------------------------------------------
// Sort 5: in-place per-bin sort by local node (block per bin, bin staged in
// LDS), emits final per-node CSR offsets. Final records carry src*128
// (byte offset of the 128B h-row) for add-only gather addressing in agg.
// ---------------------------------------------------------------------------
__global__ __launch_bounds__(256) void binsort_kernel(
    uint4* __restrict__ rec, const int* __restrict__ binOff,
    int* __restrict__ off)
{
    __shared__ uint4 buf[BCAP];
    __shared__ int cnt[128];
    __shared__ int sc[128];
    const int b = blockIdx.x, t = threadIdx.x;
    const int n0 = binOff[b];
    const int n  = binOff[b + 1] - n0;
    if (t < 128) cnt[t] = 0;
    __syncthreads();
    for (int i = t; i < n; i += 256) {
        uint4 r = rec[n0 + i];
        buf[i] = r;
        atomicAdd(&cnt[r.x >> 20], 1);
    }
    __syncthreads();
    if (t < 128) sc[t] = cnt[t];
    __syncthreads();
    for (int d = 1; d < 128; d <<= 1) {
        int v = 0;
        if (t < 128 && t >= d) v = sc[t - d];
        __syncthreads();
        if (t < 128) sc[t] += v;
        __syncthreads();
    }
    if (t < 116) {
        const int ex = sc[t] - cnt[t];
        off[b * 116 + t] = n0 + ex;
        cnt[t] = ex;                      // reuse as cursor
    }
    __syncthreads();
    for (int i = t; i < n; i += 256) {
        uint4 r = buf[i];
        const int p = atomicAdd(&cnt[r.x >> 20], 1);
        r.x = (r.x & 0xFFFFFu) << 7;      // src -> byte offset of h-row
        rec[n0 + p] = r;
    }
}

// ---------------------------------------------------------------------------
// One-time weight packer: bf16 MFMA-fragment layouts in workspace.
// ---------------------------------------------------------------------------
__global__ __launch_bounds__(256) void pack_kernel(
    const float* __restrict__ Wenc,
    const float* __restrict__ W10, const float* __restrict__ W20,
    const float* __restrict__ W1, const float* __restrict__ W2,
    unsigned short* __restrict__ WPenc, unsigned short* __restrict__ WPh)
{
    const int b = blockIdx.x, tid = threadIdx.x;
    if (b == 0) {
        for (int i = tid; i < 10240; i += 256) {
            const int j = i & 7, lane = (i >> 3) & 63, t = i >> 9;
            const int c = t / 5, s = t - c * 5;
            const int k = s * 32 + (lane >> 4) * 8 + j;
            const int n = c * 16 + (lane & 15);
            const float v = (k < 132) ? Wenc[k * 64 + n] : 0.f;
            WPenc[i] = (unsigned short)f2u(v);
        }
        return;
    }
    const float* src = nullptr;
    unsigned short* dst = nullptr;
    switch (b) {
        case 1: src = W10;       dst = WPh + 0 * 4096; break;
        case 2: src = W20;       dst = WPh + 1 * 4096; break;
        case 3: src = W1;        dst = WPh + 2 * 4096; break;
        case 4: src = W2;        dst = WPh + 3 * 4096; break;
        case 5: src = W1 + 4096; dst = WPh + 4 * 4096; break;
        case 6: src = W2 + 4096; dst = WPh + 5 * 4096; break;
        case 7: src = W1 + 8192; dst = WPh + 6 * 4096; break;
        case 8: src = W2 + 8192; dst = WPh + 7 * 4096; break;
    }
    for (int i = tid; i < 4096; i += 256) {
        const int j = i & 7, lane = (i >> 3) & 63, t = i >> 9;
        const int c = t >> 1, s = t & 1;
        const int k = s * 32 + (lane >> 4) * 8 + j;
        const int n = c * 16 + (lane & 15);
        dst[i] = (unsigned short)f2u(src[k * 64 + n]);
    }
}

// ---------------------------------------------------------------------------
// Encoder GEMM, LDS-free: A fragments built from global x/emb via float4,
// B fragments read from prepacked global (L2-broadcast). No staging barriers.
// ---------------------------------------------------------------------------
__global__ __launch_bounds__(256) void enc_kernel(
    const float* __restrict__ x, const int* __restrict__ gid,
    const float* __restrict__ emb, const unsigned short* __restrict__ WP,
    const float* __restrict__ benc,
    bf16* __restrict__ hb, float* __restrict__ stats)
{
    __shared__ float sred[4][128];

    const int tid  = threadIdx.x;
    const int lane = tid & 63;
    const int wv   = tid >> 6;
    const int m    = lane & 15;
    const int q    = lane >> 4;
    const int r0   = blockIdx.x * 64;

    const int arow = r0 + wv * 16 + m;
    const float* xr = x + (size_t)arow * INDIM;
    const float* er = emb + gid[arow] * EMBD;

    floatx4 acc[4];
    #pragma unroll
    for (int c = 0; c < 4; c++) acc[c] = {0.f, 0.f, 0.f, 0.f};

    #pragma unroll
    for (int s = 0; s < 5; s++) {
        float4 a, b;
        if (s < 3) {                                    // k in [0,96): pure x
            a = *(const float4*)(xr + s * 32 + q * 8);
            b = *(const float4*)(xr + s * 32 + q * 8 + 4);
        } else if (s == 3) {                            // k in [96,128): seam
            if (q < 2) {
                a = *(const float4*)(xr + 96 + q * 8);
                b = *(const float4*)(xr + 100 + q * 8);
            } else if (q == 2) {
                a = *(const float4*)(xr + 112);
                b = *(const float4*)(er);
            } else {
                a = *(const float4*)(er + 4);
                b = *(const float4*)(er + 8);
            }
        } else {                                        // k in [128,160)
            if (q == 0) {
                a = *(const float4*)(er + 12);
                b = make_float4(0.f, 0.f, 0.f, 0.f);
            } else {
                a = make_float4(0.f, 0.f, 0.f, 0.f);
                b = a;
            }
        }
        short8 af;
        af[0] = (short)f2u(a.x); af[1] = (short)f2u(a.y);
        af[2] = (short)f2u(a.z); af[3] = (short)f2u(a.w);
        af[4] = (short)f2u(b.x); af[5] = (short)f2u(b.y);
        af[6] = (short)f2u(b.z); af[7] = (short)f2u(b.w);
        #pragma unroll
        for (int c = 0; c < 4; c++) {
            short8 bfr = *(const short8*)(WP + (size_t)(((c * 5 + s) * 64) + lane) * 8);
            acc[c] = __builtin_amdgcn_mfma_f32_16x16x32_bf16(af, bfr, acc[c], 0, 0, 0);
        }
    }

    #pragma unroll
    for (int c = 0; c < 4; c++) {
        const int ch = c * 16 + m;
        const float bb = benc[ch];
        float sv = 0.f, sq = 0.f;
        #pragma unroll
        for (int r = 0; r < 4; r++) {
            const int orow = r0 + wv * 16 + q * 4 + r;
            float a = fmaxf(acc[c][r] + bb, 0.f);
            hb[(size_t)orow * HID + ch] = f2b(a);
            sv += a; sq += a * a;
        }
        sv += __shfl_xor(sv, 16); sv += __shfl_xor(sv, 32);
        sq += __shfl_xor(sq, 16); sq += __shfl_xor(sq, 32);
        if (q == 0) { sred[wv][ch] = sv; sred[wv][64 + ch] = sq; }
    }
    __syncthreads();
    if (tid < 128) {
        const float s = sred[0][tid] + sred[1][tid] + sred[2][tid] + sred[3][tid];
        unsafeAtomicAdd(&stats[tid], s);
    }
}

// ---------------------------------------------------------------------------
// Gather-aggregate, wave per node, fused BN-on-read.
// MODE: 0 = identity, 1 = BN, 2 = BN + relu  (applied to hin reads)
// node is wave-UNIFORM (readfirstlane) so off[]/rec[] loads go to the scalar
// pipe (s_load) and record unpacks become SALU; math is exact f32.
// ---------------------------------------------------------------------------
template <int MODE>
__global__ __launch_bounds__(256) void agg_kernel(
    const bf16* __restrict__ hin, bf16* __restrict__ zout,
    const uint4* __restrict__ rec, const int* __restrict__ off,
    const float* __restrict__ We, const float* __restrict__ be,
    const float* __restrict__ stats, const float* __restrict__ gamma,
    const float* __restrict__ beta)
{
    const int lane = threadIdx.x & 63;
    const int node = blockIdx.x * 4 + __builtin_amdgcn_readfirstlane(threadIdx.x >> 6);
    if (node >= NNODES) return;

    float gg = 1.f, bbt = 0.f;
    if (MODE != 0) {
        const float m = stats[lane] * (1.f / NNODES);
        const float var = stats[64 + lane] * (1.f / NNODES) - m * m;
        const float inv = rsqrtf(var + 1e-5f);
        gg = gamma[lane] * inv;
        bbt = beta[lane] - gg * m;
    }
    const float w0 = We[lane], w1 = We[64 + lane], w2 = We[128 + lane];
    const float w3 = We[192 + lane], w4 = We[256 + lane];
    const float bel = be[lane];

    const int s0 = off[node];
    const int s1 = off[node + 1];

    // record.x holds the h-row byte offset; per-lane part is constant (lane*2)
    const char* hlane = (const char*)hin + (lane << 1);

    float self = b2f(hin[(size_t)node * HID + lane]);
    if (MODE == 1) self = gg * self + bbt;
    if (MODE == 2) self = fmaxf(gg * self + bbt, 0.f);

    float acc = 0.f;
    int i = s0;

#define EDGE_TERM(R, HF)                                                     \
    {                                                                        \
        float hh = (HF);                                                     \
        if (MODE == 1) hh = gg * hh + bbt;                                   \
        if (MODE == 2) hh = fmaxf(gg * hh + bbt, 0.f);                       \
        const float v = bel                                                  \
            + uf((R).y << 16) * w0 + uf((R).y & 0xFFFF0000u) * w1            \
            + uf((R).z << 16) * w2 + uf((R).z & 0xFFFF0000u) * w3            \
            + uf((R).w << 16) * w4 + hh;                                     \
        acc += fmaxf(v, 0.f);                                                \
    }

    for (; i + 8 <= s1; i += 8) {
        uint4 r[8];
        #pragma unroll
        for (int j = 0; j < 8; j++) r[j] = rec[i + j];
        float h[8];
        #pragma unroll
        for (int j = 0; j < 8; j++)
            h[j] = uf((unsigned)*(const unsigned short*)(hlane + r[j].x) << 16);
        #pragma unroll
        for (int j = 0; j < 8; j++) EDGE_TERM(r[j], h[j])
    }
    for (; i + 4 <= s1; i += 4) {
        uint4 r[4];
        #pragma unroll
        for (int j = 0; j < 4; j++) r[j] = rec[i + j];
        float h[4];
        #pragma unroll
        for (int j = 0; j < 4; j++)
            h[j] = uf((unsigned)*(const unsigned short*)(hlane + r[j].x) << 16);
        #pragma unroll
        for (int j = 0; j < 4; j++) EDGE_TERM(r[j], h[j])
    }
    for (; i < s1; i++) {
        const uint4 r = rec[i];
        const float hf = uf((unsigned)*(const unsigned short*)(hlane + r.x) << 16);
        EDGE_TERM(r, hf)
    }
#undef EDGE_TERM

    zout[(size_t)node * HID + lane] = f2b(self + acc);
}

// ---------------------------------------------------------------------------
// Node MLP via MFMA, in place on Z. Weights read as prepacked bf16 fragments
// straight from global (L2-broadcast) — no per-block weight staging.
// MODE 0: z <- relu(o).  MODE 1: z <- o (pre-BN) + stats.
// ---------------------------------------------------------------------------
template <int MODE>
__global__ __launch_bounds__(256) void mlp_kernel(
    bf16* __restrict__ Zg,
    const unsigned short* __restrict__ W1P, const float* __restrict__ b1,
    const unsigned short* __restrict__ W2P, const float* __restrict__ b2,
    float* __restrict__ stats)
{
    __shared__ unsigned short Zl[64 * 72];
    __shared__ unsigned short Tl[64 * 72];
    __shared__ float sred[4][128];

    const int tid = threadIdx.x;
    const int r0 = blockIdx.x * 64;

    {
        const uint4* zg = (const uint4*)(Zg + (size_t)r0 * HID);
        for (int i = tid; i < 512; i += 256) {
            int row = i >> 3, ch = i & 7;
            *(uint4*)&Zl[row * 72 + ch * 8] = zg[row * 8 + ch];
        }
    }
    __syncthreads();

    const int lane = tid & 63;
    const int wv   = tid >> 6;
    const int m    = lane & 15;
    const int q    = lane >> 4;
    const int mrow = wv * 16;

    float bias1[4], bias2[4];
    #pragma unroll
    for (int c = 0; c < 4; c++) {
        bias1[c] = b1[c * 16 + m];
        bias2[c] = b2[c * 16 + m];
    }

    floatx4 acc[4];
    #pragma unroll
    for (int c = 0; c < 4; c++) acc[c] = {0.f, 0.f, 0.f, 0.f};
    #pragma unroll
    for (int s = 0; s < 2; s++) {
        short8 af = *(const short8*)&Zl[(mrow + m) * 72 + s * 32 + q * 8];
        #pragma unroll
        for (int c = 0; c < 4; c++) {
            short8 bfr = *(const short8*)(W1P + (size_t)(((c * 2 + s) * 64) + lane) * 8);
            acc[c] = __builtin_amdgcn_mfma_f32_16x16x32_bf16(af, bfr, acc[c], 0, 0, 0);
        }
    }
    #pragma unroll
    for (int c = 0; c < 4; c++)
        #pragma unroll
        for (int r = 0; r < 4; r++)
            Tl[(mrow + q * 4 + r) * 72 + c * 16 + m] =
                (unsigned short)f2u(fmaxf(acc[c][r] + bias1[c], 0.f));
    __syncthreads();

    #pragma unroll
    for (int c = 0; c < 4; c++) acc[c] = {0.f, 0.f, 0.f, 0.f};
    #pragma unroll
    for (int s = 0; s < 2; s++) {
        short8 af = *(const short8*)&Tl[(mrow + m) * 72 + s * 32 + q * 8];
        #pragma unroll
        for (int c = 0; c < 4; c++) {
            short8 bfr = *(const short8*)(W2P + (size_t)(((c * 2 + s) * 64) + lane) * 8);
            acc[c] = __builtin_amdgcn_mfma_f32_16x16x32_bf16(af, bfr, acc[c], 0, 0, 0);
        }
    }
    #pragma unroll
    for (int c = 0; c < 4; c++) {
        float sv = 0.f, sq = 0.f;
        #pragma unroll
        for (int r = 0; r < 4; r++) {
            float o = acc[c][r] + bias2[c];
            if (MODE == 0) o = fmaxf(o, 0.f);
            Zg[(size_t)(r0 + mrow + q * 4 + r) * HID + c * 16 + m] = f2b(o);
            if (MODE == 1) { sv += o; sq += o * o; }
        }
        if (MODE == 1) {
            sv += __shfl_xor(sv, 16); sv += __shfl_xor(sv, 32);
            sq += __shfl_xor(sq, 16); sq += __shfl_xor(sq, 32);
            if (q == 0) { sred[wv][c * 16 + m] = sv; sred[wv][64 + c * 16 + m] = sq; }
        }
    }
    if (MODE == 1) {
        __syncthreads();
        if (tid < 128) {
            const float s = sred[0][tid] + sred[1][tid] + sred[2][tid] + sred[3][tid];
            unsafeAtomicAdd(&stats[tid], s);
        }
    }
}

// ---------------------------------------------------------------------------
// Head with fused final BN+relu
// ---------------------------------------------------------------------------
__global__ __launch_bounds__(128) void head_kernel(
    const bf16* __restrict__ hb, const float* __restrict__ Wl1,
    const float* __restrict__ bl1, const float* __restrict__ Wl2,
    const float* __restrict__ bl2, float* __restrict__ out,
    const float* __restrict__ stats, const float* __restrict__ gamma,
    const float* __restrict__ beta)
{
    __shared__ float part[2 * HID];
    __shared__ float ps[HID];
    __shared__ float r0[128], r1[128];

    const int g = blockIdx.x;
    const int tid = threadIdx.x;
    const int lane = tid & 63;
    const int wv = tid >> 6;
    const bf16* hbg = hb + (size_t)g * ROIS * HID;

    const float mm = stats[lane] * (1.f / NNODES);
    const float var = stats[64 + lane] * (1.f / NNODES) - mm * mm;
    const float inv = rsqrtf(var + 1e-5f);
    const float gg = gamma[lane] * inv;
    const float bbt = beta[lane] - gg * mm;

    float acc = 0.f;
    for (int r = wv; r < ROIS; r += 2)
        acc += fmaxf(gg * b2f(hbg[r * HID + lane]) + bbt, 0.f);
    part[wv * HID + lane] = acc;
    __syncthreads();
    if (tid < HID) ps[tid] = fmaxf(part[tid] + part[HID + tid], 0.f);
    __syncthreads();

    float e0 = 0.f, e1 = 0.f;
    if (tid < ROIS) {
        float a = bl1[tid];
        #pragma unroll 8
        for (int c = 0; c < HID; c++)
            a += ps[c] * Wl1[c * ROIS + tid];
        e0 = a * Wl2[tid * 2 + 0];
        e1 = a * Wl2[tid * 2 + 1];
    }
    r0[tid] = e0;
    r1[tid] = e1;
    __syncthreads();
    for (int s = 64; s > 0; s >>= 1) {
        if (tid < s) { r0[tid] += r0[tid + s]; r1[tid] += r1[tid + s]; }
        __syncthreads();
    }
    if (tid == 0) {
        out[g * 2 + 0] = r0[0] + bl2[0];
        out[g * 2 + 1] = r1[0] + bl2[1];
    }
}

// ---------------------------------------------------------------------------
extern "C" void kernel_launch(void* const* d_in, const int* in_sizes, int n_in,
                              void* d_out, int out_size, void* d_ws, size_t ws_size,
                              hipStream_t stream)
{
    const float* x       = (const float*)d_in[0];
    const float* ea      = (const float*)d_in[1];
    const int*   eidx    = (const int*)  d_in[2];
    const int*   gid     = (const int*)  d_in[4];
    const float* emb     = (const float*)d_in[5];
    const float* Wenc    = (const float*)d_in[6];
    const float* benc    = (const float*)d_in[7];
    const float* gamma_e = (const float*)d_in[8];
    const float* beta_e  = (const float*)d_in[9];
    const float* We0     = (const float*)d_in[10];
    const float* be0     = (const float*)d_in[11];
    const float* W10     = (const float*)d_in[12];
    const float* b10     = (const float*)d_in[13];
    const float* W20     = (const float*)d_in[14];
    const float* b20     = (const float*)d_in[15];
    const float* We      = (const float*)d_in[16];
    const float* be      = (const float*)d_in[17];
    const float* W1      = (const float*)d_in[18];
    const float* b1      = (const float*)d_in[19];
    const float* W2      = (const float*)d_in[20];
    const float* b2      = (const float*)d_in[21];
    const float* gamma   = (const float*)d_in[22];
    const float* beta    = (const float*)d_in[23];
    const float* Wl1     = (const float*)d_in[24];
    const float* bl1     = (const float*)d_in[25];
    const float* Wl2     = (const float*)d_in[26];
    const float* bl2     = (const float*)d_in[27];

    const int* srcp = eidx;
    const int* dstp = eidx + NEDGES;

    // workspace (~82 MB):
    // A | Z | rec | off | binCnt | binOff | cntMat | stats | WPenc | WPh
    const size_t NH = (size_t)NNODES * HID;
    char* p = (char*)d_ws;
    bf16*  Abuf = (bf16*)p;  p += NH * 2;
    bf16*  Zbuf = (bf16*)p;  p += NH * 2;
    uint4* rec  = (uint4*)p; p += (size_t)NEDGES * 16;
    int* off    = (int*)p;   p += (size_t)(NNODES + 16) * 4;
    int* binCnt = (int*)p;   p += (NBINS + 16) * 4;
    int* binOff = (int*)p;   p += (NBINS + 16) * 4;
    int* cntMat = (int*)p;   p += (size_t)NBINS * NBLKC_PAD * 4;
    float* stats = (float*)p; p += 512 * 4;
    unsigned short* WPenc = (unsigned short*)p; p += 10240 * 2;
    unsigned short* WPh   = (unsigned short*)p; p += 8 * 4096 * 2;

    hipMemsetAsync(stats, 0, 512 * 4, stream);

    const int nb = NNODES / 4;                 // 29696 blocks, 4 nodes each

    // ---- one-time weight packing (overlaps the edge sort) ----
    pack_kernel<<<9, 256, 0, stream>>>(Wenc, W10, W20, W1, W2, WPenc, WPh);

    // ---- counting-sort of edges by dst (no global atomics) ----
    bincnt_kernel<<<NBLKC, 256, 0, stream>>>(dstp, cntMat);
    colscan_kernel<<<NBINS, 256, 0, stream>>>(cntMat, binCnt);
    binscan_kernel<<<1, 256, 0, stream>>>(binCnt, binOff, off + NNODES);
    binplace_kernel<<<NBLKC, 256, 0, stream>>>(srcp, dstp, ea, cntMat, binOff, rec);
    binsort_kernel<<<NBINS, 256, 0, stream>>>(rec, binOff, off);

    // ---- encoder (pre-BN + stats0) ----
    enc_kernel<<<NNODES / 64, 256, 0, stream>>>(x, gid, emb, WPenc, benc, Abuf, stats);

    // ---- GINE layer 0: T = BN_e (no relu); mlp relu ----
    agg_kernel<1><<<nb, 256, 0, stream>>>(Abuf, Zbuf, rec, off, We0, be0,
                                          stats, gamma_e, beta_e);
    mlp_kernel<0><<<NNODES / 64, 256, 0, stream>>>(Zbuf, WPh + 0 * 4096, b10,
                                                   WPh + 1 * 4096, b20, nullptr);

    // ---- GINE layer 1: identity T (input already relu'd); stats1 ----
    agg_kernel<0><<<nb, 256, 0, stream>>>(Zbuf, Abuf, rec, off, We, be,
                                          nullptr, nullptr, nullptr);
    mlp_kernel<1><<<NNODES / 64, 256, 0, stream>>>(Abuf, WPh + 2 * 4096, b1,
                                                   WPh + 3 * 4096, b2, stats + 128);

    // ---- GINE layer 2: T = BN+relu (stats1); stats2 ----
    agg_kernel<2><<<nb, 256, 0, stream>>>(Abuf, Zbuf, rec, off,
                                          We + 320, be + 64,
                                          stats + 128, gamma, beta);
    mlp_kernel<1><<<NNODES / 64, 256, 0, stream>>>(Zbuf, WPh + 4 * 4096, b1 + 64,
                                                   WPh + 5 * 4096, b2 + 64, stats + 256);

    // ---- GINE layer 3: T = BN+relu (stats2); stats3 ----
    agg_kernel<2><<<nb, 256, 0, stream>>>(Zbuf, Abuf, rec, off,
                                          We + 640, be + 128,
                                          stats + 256, gamma, beta);
    mlp_kernel<1><<<NNODES / 64, 256, 0, stream>>>(Abuf, WPh + 6 * 4096, b1 + 128,
                                                   WPh + 7 * 4096, b2 + 128, stats + 384);

    // ---- pooling + head (fused final BN+relu, stats3) ----
    head_kernel<<<NGRAPH, 128, 0, stream>>>(Abuf, Wl1, bl1, Wl2, bl2,
                                            (float*)d_out, stats + 384, gamma, beta);
}

// Round 9
// 866.026 us; speedup vs baseline: 1.4465x; 1.0025x over previous
//
#include <hip/hip_runtime.h>
#include <hip/hip_bf16.h>

typedef __hip_bfloat16 bf16;
typedef __attribute__((ext_vector_type(8))) short short8;
typedef __attribute__((ext_vector_type(4))) float floatx4;

#define NNODES 118784
#define NEDGES 3000000
#define INDIM 116
#define EMBD 16
#define HID 64
#define NGRAPH 1024
#define ROIS 116
#define NBINS 1024      // 116 nodes per bin
#define BCAP 3344       // per-bin LDS cap: 53.5KB -> 3 blocks/CU.
                        // bin ~ N(2930, 54^2); P(any bin > 3344) ~ 1e-11
#define CBLK 4096       // edges per counting/placement block
#define NBLKC 733       // ceil(NEDGES / CBLK)
#define NBLKC_PAD 736

__device__ __forceinline__ float b2f(bf16 v) { return __bfloat162float(v); }
__device__ __forceinline__ bf16 f2b(float v) { return __float2bfloat16(v); }
__device__ __forceinline__ unsigned f2u(float v) {
    bf16 b = __float2bfloat16(v);
    return (unsigned)*reinterpret_cast<unsigned short*>(&b);
}
__device__ __forceinline__ float uf(unsigned u) { return __uint_as_float(u); }

// ---------------------------------------------------------------------------
// Sort 1: per-(block,bin) histogram -> cntMat[bin][blk]. No global atomics.
// ---------------------------------------------------------------------------
__global__ __launch_bounds__(256) void bincnt_kernel(
    const int* __restrict__ dst, int* __restrict__ cntMat)
{
    __shared__ int h[NBINS];
    for (int i = threadIdx.x; i < NBINS; i += 256) h[i] = 0;
    __syncthreads();
    const int base = blockIdx.x * CBLK;
    const int end = min(base + CBLK, NEDGES);
    for (int i = base + threadIdx.x; i < end; i += 256)
        atomicAdd(&h[(unsigned)dst[i] / 116u], 1);
    __syncthreads();
    for (int i = threadIdx.x; i < NBINS; i += 256)
        cntMat[i * NBLKC_PAD + blockIdx.x] = h[i];
}

// ---------------------------------------------------------------------------
// Sort 2: per-bin exclusive scan across blocks (in place), totals -> binCnt.
// ---------------------------------------------------------------------------
__global__ __launch_bounds__(256) void colscan_kernel(
    int* __restrict__ cntMat, int* __restrict__ binCnt)
{
    __shared__ int sd[256];
    int* row = cntMat + blockIdx.x * NBLKC_PAD;
    const int t = threadIdx.x;
    int v[3]; int s = 0;
    #pragma unroll
    for (int j = 0; j < 3; j++) {
        const int idx = t * 3 + j;
        v[j] = (idx < NBLKC) ? row[idx] : 0;
        s += v[j];
    }
    sd[t] = s;
    __syncthreads();
    for (int d = 1; d < 256; d <<= 1) {
        int x = (t >= d) ? sd[t - d] : 0;
        __syncthreads();
        sd[t] += x;
        __syncthreads();
    }
    int ex = (t == 0) ? 0 : sd[t - 1];
    #pragma unroll
    for (int j = 0; j < 3; j++) {
        const int idx = t * 3 + j;
        if (idx < NBLKC) { const int val = v[j]; row[idx] = ex; ex += val; }
    }
    if (t == 255) binCnt[blockIdx.x] = ex;
}

// ---------------------------------------------------------------------------
// Sort 3: exclusive scan of 1024 bin totals (1 block)
// ---------------------------------------------------------------------------
__global__ __launch_bounds__(256) void binscan_kernel(
    const int* __restrict__ binCnt, int* __restrict__ binOff,
    int* __restrict__ offN)
{
    __shared__ int sd[256];
    const int t = threadIdx.x;
    int c[4]; int s = 0;
    #pragma unroll
    for (int j = 0; j < 4; j++) { c[j] = binCnt[t * 4 + j]; s += c[j]; }
    sd[t] = s;
    __syncthreads();
    for (int d = 1; d < 256; d <<= 1) {
        int v = (t >= d) ? sd[t - d] : 0;
        __syncthreads();
        sd[t] += v;
        __syncthreads();
    }
    int ex = (t == 0) ? 0 : sd[t - 1];
    #pragma unroll
    for (int j = 0; j < 4; j++) { binOff[t * 4 + j] = ex; ex += c[j]; }
    if (t == 0) { binOff[NBINS] = NEDGES; offN[0] = NEDGES; }
}

// ---------------------------------------------------------------------------
// Sort 4: deterministic placement. LDS cursors seeded from cntMat+binOff;
// zero global atomics. record = {src | dstLocal<<20, ea0|ea1, ea2|ea3, ea4}
// ---------------------------------------------------------------------------
__global__ __launch_bounds__(256) void binplace_kernel(
    const int* __restrict__ src, const int* __restrict__ dst,
    const float* __restrict__ ea, const int* __restrict__ posMat,
    const int* __restrict__ binOff, uint4* __restrict__ rec)
{
    __shared__ int cursor[NBINS];
    const int blk = blockIdx.x;
    for (int i = threadIdx.x; i < NBINS; i += 256)
        cursor[i] = posMat[i * NBLKC_PAD + blk] + binOff[i];
    __syncthreads();
    const int base = blk * CBLK;
    const int end = min(base + CBLK, NEDGES);
    for (int e = base + threadIdx.x; e < end; e += 256) {
        const unsigned d = (unsigned)dst[e];
        const unsigned bin = d / 116u;
        const unsigned dl = d - bin * 116u;
        const float* a = ea + (size_t)e * 5;
        const unsigned m0 = f2u(a[0]) | (f2u(a[1]) << 16);
        const unsigned m1 = f2u(a[2]) | (f2u(a[3]) << 16);
        const unsigned m2 = f2u(a[4]);
        const int p = atomicAdd(&cursor[bin], 1);
        rec[p] = make_uint4((unsigned)src[e] | (dl << 20), m0, m1, m2);
    }
}

// ---------------------------------------------------------------------------
// Sort 5: in-place per-bin sort by local node (block per bin, bin staged in
// LDS), emits final per-node CSR offsets. Final records carry src*128
// (byte offset of the 128B h-row) for add-only gather addressing in agg.
// LDS 54.5KB -> 3 blocks/CU.
// ---------------------------------------------------------------------------
__global__ __launch_bounds__(256) void binsort_kernel(
    uint4* __restrict__ rec, const int* __restrict__ binOff,
    int* __restrict__ off)
{
    __shared__ uint4 buf[BCAP];
    __shared__ int cnt[128];
    __shared__ int sc[128];
    const int b = blockIdx.x, t = threadIdx.x;
    const int n0 = binOff[b];
    const int n  = binOff[b + 1] - n0;
    if (t < 128) cnt[t] = 0;
    __syncthreads();
    for (int i = t; i < n; i += 256) {
        uint4 r = rec[n0 + i];
        buf[i] = r;
        atomicAdd(&cnt[r.x >> 20], 1);
    }
    __syncthreads();
    if (t < 128) sc[t] = cnt[t];
    __syncthreads();
    for (int d = 1; d < 128; d <<= 1) {
        int v = 0;
        if (t < 128 && t >= d) v = sc[t - d];
        __syncthreads();
        if (t < 128) sc[t] += v;
        __syncthreads();
    }
    if (t < 116) {
        const int ex = sc[t] - cnt[t];
        off[b * 116 + t] = n0 + ex;
        cnt[t] = ex;                      // reuse as cursor
    }
    __syncthreads();
    for (int i = t; i < n; i += 256) {
        uint4 r = buf[i];
        const int p = atomicAdd(&cnt[r.x >> 20], 1);
        r.x = (r.x & 0xFFFFFu) << 7;      // src -> byte offset of h-row
        rec[n0 + p] = r;
    }
}

// ---------------------------------------------------------------------------
// One-time weight packer: bf16 MFMA-fragment layouts in workspace.
// Block 9 zeros the stats accumulators (replaces a memset dispatch).
// ---------------------------------------------------------------------------
__global__ __launch_bounds__(256) void pack_kernel(
    const float* __restrict__ Wenc,
    const float* __restrict__ W10, const float* __restrict__ W20,
    const float* __restrict__ W1, const float* __restrict__ W2,
    unsigned short* __restrict__ WPenc, unsigned short* __restrict__ WPh,
    float* __restrict__ stats)
{
    const int b = blockIdx.x, tid = threadIdx.x;
    if (b == 9) {
        stats[tid] = 0.f;
        stats[256 + tid] = 0.f;
        return;
    }
    if (b == 0) {
        for (int i = tid; i < 10240; i += 256) {
            const int j = i & 7, lane = (i >> 3) & 63, t = i >> 9;
            const int c = t / 5, s = t - c * 5;
            const int k = s * 32 + (lane >> 4) * 8 + j;
            const int n = c * 16 + (lane & 15);
            const float v = (k < 132) ? Wenc[k * 64 + n] : 0.f;
            WPenc[i] = (unsigned short)f2u(v);
        }
        return;
    }
    const float* src = nullptr;
    unsigned short* dst = nullptr;
    switch (b) {
        case 1: src = W10;       dst = WPh + 0 * 4096; break;
        case 2: src = W20;       dst = WPh + 1 * 4096; break;
        case 3: src = W1;        dst = WPh + 2 * 4096; break;
        case 4: src = W2;        dst = WPh + 3 * 4096; break;
        case 5: src = W1 + 4096; dst = WPh + 4 * 4096; break;
        case 6: src = W2 + 4096; dst = WPh + 5 * 4096; break;
        case 7: src = W1 + 8192; dst = WPh + 6 * 4096; break;
        case 8: src = W2 + 8192; dst = WPh + 7 * 4096; break;
    }
    for (int i = tid; i < 4096; i += 256) {
        const int j = i & 7, lane = (i >> 3) & 63, t = i >> 9;
        const int c = t >> 1, s = t & 1;
        const int k = s * 32 + (lane >> 4) * 8 + j;
        const int n = c * 16 + (lane & 15);
        dst[i] = (unsigned short)f2u(src[k * 64 + n]);
    }
}

// ---------------------------------------------------------------------------
// Encoder GEMM, LDS-free: A fragments built from global x/emb via float4,
// B fragments read from prepacked global (L2-broadcast). No staging barriers.
// ---------------------------------------------------------------------------
__global__ __launch_bounds__(256) void enc_kernel(
    const float* __restrict__ x, const int* __restrict__ gid,
    const float* __restrict__ emb, const unsigned short* __restrict__ WP,
    const float* __restrict__ benc,
    bf16* __restrict__ hb, float* __restrict__ stats)
{
    __shared__ float sred[4][128];

    const int tid  = threadIdx.x;
    const int lane = tid & 63;
    const int wv   = tid >> 6;
    const int m    = lane & 15;
    const int q    = lane >> 4;
    const int r0   = blockIdx.x * 64;

    const int arow = r0 + wv * 16 + m;
    const float* xr = x + (size_t)arow * INDIM;
    const float* er = emb + gid[arow] * EMBD;

    floatx4 acc[4];
    #pragma unroll
    for (int c = 0; c < 4; c++) acc[c] = {0.f, 0.f, 0.f, 0.f};

    #pragma unroll
    for (int s = 0; s < 5; s++) {
        float4 a, b;
        if (s < 3) {                                    // k in [0,96): pure x
            a = *(const float4*)(xr + s * 32 + q * 8);
            b = *(const float4*)(xr + s * 32 + q * 8 + 4);
        } else if (s == 3) {                            // k in [96,128): seam
            if (q < 2) {
                a = *(const float4*)(xr + 96 + q * 8);
                b = *(const float4*)(xr + 100 + q * 8);
            } else if (q == 2) {
                a = *(const float4*)(xr + 112);
                b = *(const float4*)(er);
            } else {
                a = *(const float4*)(er + 4);
                b = *(const float4*)(er + 8);
            }
        } else {                                        // k in [128,160)
            if (q == 0) {
                a = *(const float4*)(er + 12);
                b = make_float4(0.f, 0.f, 0.f, 0.f);
            } else {
                a = make_float4(0.f, 0.f, 0.f, 0.f);
                b = a;
            }
        }
        short8 af;
        af[0] = (short)f2u(a.x); af[1] = (short)f2u(a.y);
        af[2] = (short)f2u(a.z); af[3] = (short)f2u(a.w);
        af[4] = (short)f2u(b.x); af[5] = (short)f2u(b.y);
        af[6] = (short)f2u(b.z); af[7] = (short)f2u(b.w);
        #pragma unroll
        for (int c = 0; c < 4; c++) {
            short8 bfr = *(const short8*)(WP + (size_t)(((c * 5 + s) * 64) + lane) * 8);
            acc[c] = __builtin_amdgcn_mfma_f32_16x16x32_bf16(af, bfr, acc[c], 0, 0, 0);
        }
    }

    #pragma unroll
    for (int c = 0; c < 4; c++) {
        const int ch = c * 16 + m;
        const float bb = benc[ch];
        float sv = 0.f, sq = 0.f;
        #pragma unroll
        for (int r = 0; r < 4; r++) {
            const int orow = r0 + wv * 16 + q * 4 + r;
            float a = fmaxf(acc[c][r] + bb, 0.f);
            hb[(size_t)orow * HID + ch] = f2b(a);
            sv += a; sq += a * a;
        }
        sv += __shfl_xor(sv, 16); sv += __shfl_xor(sv, 32);
        sq += __shfl_xor(sq, 16); sq += __shfl_xor(sq, 32);
        if (q == 0) { sred[wv][ch] = sv; sred[wv][64 + ch] = sq; }
    }
    __syncthreads();
    if (tid < 128) {
        const float s = sred[0][tid] + sred[1][tid] + sred[2][tid] + sred[3][tid];
        unsafeAtomicAdd(&stats[tid], s);
    }
}

// ---------------------------------------------------------------------------
// Gather-aggregate, wave per node, fused BN-on-read.
// MODE: 0 = identity, 1 = BN, 2 = BN + relu  (applied to hin reads)
// node is wave-UNIFORM (readfirstlane) so off[]/rec[] loads go to the scalar
// pipe (s_load) and record unpacks become SALU; math is exact f32.
// ---------------------------------------------------------------------------
template <int MODE>
__global__ __launch_bounds__(256) void agg_kernel(
    const bf16* __restrict__ hin, bf16* __restrict__ zout,
    const uint4* __restrict__ rec, const int* __restrict__ off,
    const float* __restrict__ We, const float* __restrict__ be,
    const float* __restrict__ stats, const float* __restrict__ gamma,
    const float* __restrict__ beta)
{
    const int lane = threadIdx.x & 63;
    const int node = blockIdx.x * 4 + __builtin_amdgcn_readfirstlane(threadIdx.x >> 6);
    if (node >= NNODES) return;

    float gg = 1.f, bbt = 0.f;
    if (MODE != 0) {
        const float m = stats[lane] * (1.f / NNODES);
        const float var = stats[64 + lane] * (1.f / NNODES) - m * m;
        const float inv = rsqrtf(var + 1e-5f);
        gg = gamma[lane] * inv;
        bbt = beta[lane] - gg * m;
    }
    const float w0 = We[lane], w1 = We[64 + lane], w2 = We[128 + lane];
    const float w3 = We[192 + lane], w4 = We[256 + lane];
    const float bel = be[lane];

    const int s0 = off[node];
    const int s1 = off[node + 1];

    // record.x holds the h-row byte offset; per-lane part is constant (lane*2)
    const char* hlane = (const char*)hin + (lane << 1);

    float self = b2f(hin[(size_t)node * HID + lane]);
    if (MODE == 1) self = gg * self + bbt;
    if (MODE == 2) self = fmaxf(gg * self + bbt, 0.f);

    float acc = 0.f;
    int i = s0;

#define EDGE_TERM(R, HF)                                                     \
    {                                                                        \
        float hh = (HF);                                                     \
        if (MODE == 1) hh = gg * hh + bbt;                                   \
        if (MODE == 2) hh = fmaxf(gg * hh + bbt, 0.f);                       \
        const float v = bel                                                  \
            + uf((R).y << 16) * w0 + uf((R).y & 0xFFFF0000u) * w1            \
            + uf((R).z << 16) * w2 + uf((R).z & 0xFFFF0000u) * w3            \
            + uf((R).w << 16) * w4 + hh;                                     \
        acc += fmaxf(v, 0.f);                                                \
    }

    for (; i + 8 <= s1; i += 8) {
        uint4 r[8];
        #pragma unroll
        for (int j = 0; j < 8; j++) r[j] = rec[i + j];
        float h[8];
        #pragma unroll
        for (int j = 0; j < 8; j++)
            h[j] = uf((unsigned)*(const unsigned short*)(hlane + r[j].x) << 16);
        #pragma unroll
        for (int j = 0; j < 8; j++) EDGE_TERM(r[j], h[j])
    }
    for (; i + 4 <= s1; i += 4) {
        uint4 r[4];
        #pragma unroll
        for (int j = 0; j < 4; j++) r[j] = rec[i + j];
        float h[4];
        #pragma unroll
        for (int j = 0; j < 4; j++)
            h[j] = uf((unsigned)*(const unsigned short*)(hlane + r[j].x) << 16);
        #pragma unroll
        for (int j = 0; j < 4; j++) EDGE_TERM(r[j], h[j])
    }
    for (; i < s1; i++) {
        const uint4 r = rec[i];
        const float hf = uf((unsigned)*(const unsigned short*)(hlane + r.x) << 16);
        EDGE_TERM(r, hf)
    }
#undef EDGE_TERM

    zout[(size_t)node * HID + lane] = f2b(self + acc);
}

// ---------------------------------------------------------------------------
// Node MLP via MFMA, in place on Z. Weights read as prepacked bf16 fragments
// straight from global (L2-broadcast) — no per-block weight staging.
// MODE 0: z <- relu(o).  MODE 1: z <- o (pre-BN) + stats.
// ---------------------------------------------------------------------------
template <int MODE>
__global__ __launch_bounds__(256) void mlp_kernel(
    bf16* __restrict__ Zg,
    const unsigned short* __restrict__ W1P, const float* __restrict__ b1,
    const unsigned short* __restrict__ W2P, const float* __restrict__ b2,
    float* __restrict__ stats)
{
    __shared__ unsigned short Zl[64 * 72];
    __shared__ unsigned short Tl[64 * 72];
    __shared__ float sred[4][128];

    const int tid = threadIdx.x;
    const int r0 = blockIdx.x * 64;

    {
        const uint4* zg = (const uint4*)(Zg + (size_t)r0 * HID);
        for (int i = tid; i < 512; i += 256) {
            int row = i >> 3, ch = i & 7;
            *(uint4*)&Zl[row * 72 + ch * 8] = zg[row * 8 + ch];
        }
    }
    __syncthreads();

    const int lane = tid & 63;
    const int wv   = tid >> 6;
    const int m    = lane & 15;
    const int q    = lane >> 4;
    const int mrow = wv * 16;

    float bias1[4], bias2[4];
    #pragma unroll
    for (int c = 0; c < 4; c++) {
        bias1[c] = b1[c * 16 + m];
        bias2[c] = b2[c * 16 + m];
    }

    floatx4 acc[4];
    #pragma unroll
    for (int c = 0; c < 4; c++) acc[c] = {0.f, 0.f, 0.f, 0.f};
    #pragma unroll
    for (int s = 0; s < 2; s++) {
        short8 af = *(const short8*)&Zl[(mrow + m) * 72 + s * 32 + q * 8];
        #pragma unroll
        for (int c = 0; c < 4; c++) {
            short8 bfr = *(const short8*)(W1P + (size_t)(((c * 2 + s) * 64) + lane) * 8);
            acc[c] = __builtin_amdgcn_mfma_f32_16x16x32_bf16(af, bfr, acc[c], 0, 0, 0);
        }
    }
    #pragma unroll
    for (int c = 0; c < 4; c++)
        #pragma unroll
        for (int r = 0; r < 4; r++)
            Tl[(mrow + q * 4 + r) * 72 + c * 16 + m] =
                (unsigned short)f2u(fmaxf(acc[c][r] + bias1[c], 0.f));
    __syncthreads();

    #pragma unroll
    for (int c = 0; c < 4; c++) acc[c] = {0.f, 0.f, 0.f, 0.f};
    #pragma unroll
    for (int s = 0; s < 2; s++) {
        short8 af = *(const short8*)&Tl[(mrow + m) * 72 + s * 32 + q * 8];
        #pragma unroll
        for (int c = 0; c < 4; c++) {
            short8 bfr = *(const short8*)(W2P + (size_t)(((c * 2 + s) * 64) + lane) * 8);
            acc[c] = __builtin_amdgcn_mfma_f32_16x16x32_bf16(af, bfr, acc[c], 0, 0, 0);
        }
    }
    #pragma unroll
    for (int c = 0; c < 4; c++) {
        float sv = 0.f, sq = 0.f;
        #pragma unroll
        for (int r = 0; r < 4; r++) {
            float o = acc[c][r] + bias2[c];
            if (MODE == 0) o = fmaxf(o, 0.f);
            Zg[(size_t)(r0 + mrow + q * 4 + r) * HID + c * 16 + m] = f2b(o);
            if (MODE == 1) { sv += o; sq += o * o; }
        }
        if (MODE == 1) {
            sv += __shfl_xor(sv, 16); sv += __shfl_xor(sv, 32);
            sq += __shfl_xor(sq, 16); sq += __shfl_xor(sq, 32);
            if (q == 0) { sred[wv][c * 16 + m] = sv; sred[wv][64 + c * 16 + m] = sq; }
        }
    }
    if (MODE == 1) {
        __syncthreads();
        if (tid < 128) {
            const float s = sred[0][tid] + sred[1][tid] + sred[2][tid] + sred[3][tid];
            unsafeAtomicAdd(&stats[tid], s);
        }
    }
}

// ---------------------------------------------------------------------------
// Head with fused final BN+relu
// ---------------------------------------------------------------------------
__global__ __launch_bounds__(128) void head_kernel(
    const bf16* __restrict__ hb, const float* __restrict__ Wl1,
    const float* __restrict__ bl1, const float* __restrict__ Wl2,
    const float* __restrict__ bl2, float* __restrict__ out,
    const float* __restrict__ stats, const float* __restrict__ gamma,
    const float* __restrict__ beta)
{
    __shared__ float part[2 * HID];
    __shared__ float ps[HID];
    __shared__ float r0[128], r1[128];

    const int g = blockIdx.x;
    const int tid = threadIdx.x;
    const int lane = tid & 63;
    const int wv = tid >> 6;
    const bf16* hbg = hb + (size_t)g * ROIS * HID;

    const float mm = stats[lane] * (1.f / NNODES);
    const float var = stats[64 + lane] * (1.f / NNODES) - mm * mm;
    const float inv = rsqrtf(var + 1e-5f);
    const float gg = gamma[lane] * inv;
    const float bbt = beta[lane] - gg * mm;

    float acc = 0.f;
    for (int r = wv; r < ROIS; r += 2)
        acc += fmaxf(gg * b2f(hbg[r * HID + lane]) + bbt, 0.f);
    part[wv * HID + lane] = acc;
    __syncthreads();
    if (tid < HID) ps[tid] = fmaxf(part[tid] + part[HID + tid], 0.f);
    __syncthreads();

    float e0 = 0.f, e1 = 0.f;
    if (tid < ROIS) {
        float a = bl1[tid];
        #pragma unroll 8
        for (int c = 0; c < HID; c++)
            a += ps[c] * Wl1[c * ROIS + tid];
        e0 = a * Wl2[tid * 2 + 0];
        e1 = a * Wl2[tid * 2 + 1];
    }
    r0[tid] = e0;
    r1[tid] = e1;
    __syncthreads();
    for (int s = 64; s > 0; s >>= 1) {
        if (tid < s) { r0[tid] += r0[tid + s]; r1[tid] += r1[tid + s]; }
        __syncthreads();
    }
    if (tid == 0) {
        out[g * 2 + 0] = r0[0] + bl2[0];
        out[g * 2 + 1] = r1[0] + bl2[1];
    }
}

// ---------------------------------------------------------------------------
extern "C" void kernel_launch(void* const* d_in, const int* in_sizes, int n_in,
                              void* d_out, int out_size, void* d_ws, size_t ws_size,
                              hipStream_t stream)
{
    const float* x       = (const float*)d_in[0];
    const float* ea      = (const float*)d_in[1];
    const int*   eidx    = (const int*)  d_in[2];
    const int*   gid     = (const int*)  d_in[4];
    const float* emb     = (const float*)d_in[5];
    const float* Wenc    = (const float*)d_in[6];
    const float* benc    = (const float*)d_in[7];
    const float* gamma_e = (const float*)d_in[8];
    const float* beta_e  = (const float*)d_in[9];
    const float* We0     = (const float*)d_in[10];
    const float* be0     = (const float*)d_in[11];
    const float* W10     = (const float*)d_in[12];
    const float* b10     = (const float*)d_in[13];
    const float* W20     = (const float*)d_in[14];
    const float* b20     = (const float*)d_in[15];
    const float* We      = (const float*)d_in[16];
    const float* be      = (const float*)d_in[17];
    const float* W1      = (const float*)d_in[18];
    const float* b1      = (const float*)d_in[19];
    const float* W2      = (const float*)d_in[20];
    const float* b2      = (const float*)d_in[21];
    const float* gamma   = (const float*)d_in[22];
    const float* beta    = (const float*)d_in[23];
    const float* Wl1     = (const float*)d_in[24];
    const float* bl1     = (const float*)d_in[25];
    const float* Wl2     = (const float*)d_in[26];
    const float* bl2     = (const float*)d_in[27];

    const int* srcp = eidx;
    const int* dstp = eidx + NEDGES;

    // workspace (~82 MB):
    // A | Z | rec | off | binCnt | binOff | cntMat | stats | WPenc | WPh
    const size_t NH = (size_t)NNODES * HID;
    char* p = (char*)d_ws;
    bf16*  Abuf = (bf16*)p;  p += NH * 2;
    bf16*  Zbuf = (bf16*)p;  p += NH * 2;
    uint4* rec  = (uint4*)p; p += (size_t)NEDGES * 16;
    int* off    = (int*)p;   p += (size_t)(NNODES + 16) * 4;
    int* binCnt = (int*)p;   p += (NBINS + 16) * 4;
    int* binOff = (int*)p;   p += (NBINS + 16) * 4;
    int* cntMat = (int*)p;   p += (size_t)NBINS * NBLKC_PAD * 4;
    float* stats = (float*)p; p += 512 * 4;
    unsigned short* WPenc = (unsigned short*)p; p += 10240 * 2;
    unsigned short* WPh   = (unsigned short*)p; p += 8 * 4096 * 2;

    const int nb = NNODES / 4;                 // 29696 blocks, 4 nodes each

    // ---- one-time weight packing + stats zeroing (overlaps the edge sort) --
    pack_kernel<<<10, 256, 0, stream>>>(Wenc, W10, W20, W1, W2, WPenc, WPh, stats);

    // ---- counting-sort of edges by dst (no global atomics) ----
    bincnt_kernel<<<NBLKC, 256, 0, stream>>>(dstp, cntMat);
    colscan_kernel<<<NBINS, 256, 0, stream>>>(cntMat, binCnt);
    binscan_kernel<<<1, 256, 0, stream>>>(binCnt, binOff, off + NNODES);
    binplace_kernel<<<NBLKC, 256, 0, stream>>>(srcp, dstp, ea, cntMat, binOff, rec);
    binsort_kernel<<<NBINS, 256, 0, stream>>>(rec, binOff, off);

    // ---- encoder (pre-BN + stats0) ----
    enc_kernel<<<NNODES / 64, 256, 0, stream>>>(x, gid, emb, WPenc, benc, Abuf, stats);

    // ---- GINE layer 0: T = BN_e (no relu); mlp relu ----
    agg_kernel<1><<<nb, 256, 0, stream>>>(Abuf, Zbuf, rec, off, We0, be0,
                                          stats, gamma_e, beta_e);
    mlp_kernel<0><<<NNODES / 64, 256, 0, stream>>>(Zbuf, WPh + 0 * 4096, b10,
                                                   WPh + 1 * 4096, b20, nullptr);

    // ---- GINE layer 1: identity T (input already relu'd); stats1 ----
    agg_kernel<0><<<nb, 256, 0, stream>>>(Zbuf, Abuf, rec, off, We, be,
                                          nullptr, nullptr, nullptr);
    mlp_kernel<1><<<NNODES / 64, 256, 0, stream>>>(Abuf, WPh + 2 * 4096, b1,
                                                   WPh + 3 * 4096, b2, stats + 128);

    // ---- GINE layer 2: T = BN+relu (stats1); stats2 ----
    agg_kernel<2><<<nb, 256, 0, stream>>>(Abuf, Zbuf, rec, off,
                                          We + 320, be + 64,
                                          stats + 128, gamma, beta);
    mlp_kernel<1><<<NNODES / 64, 256, 0, stream>>>(Zbuf, WPh + 4 * 4096, b1 + 64,
                                                   WPh + 5 * 4096, b2 + 64, stats + 256);

    // ---- GINE layer 3: T = BN+relu (stats2); stats3 ----
    agg_kernel<2><<<nb, 256, 0, stream>>>(Zbuf, Abuf, rec, off,
                                          We + 640, be + 128,
                                          stats + 256, gamma, beta);
    mlp_kernel<1><<<NNODES / 64, 256, 0, stream>>>(Abuf, WPh + 6 * 4096, b1 + 128,
                                                   WPh + 7 * 4096, b2 + 128, stats + 384);

    // ---- pooling + head (fused final BN+relu, stats3) ----
    head_kernel<<<NGRAPH, 128, 0, stream>>>(Abuf, Wl1, bl1, Wl2, bl2,
                                            (float*)d_out, stats + 384, gamma, beta);
}